// Round 6
// baseline (293.748 us; speedup 1.0000x reference)
//
#include <hip/hip_runtime.h>
#include <hip/hip_bf16.h>

typedef __bf16 bf16x8 __attribute__((ext_vector_type(8)));
typedef __bf16 bf16x4_t __attribute__((ext_vector_type(4)));
typedef short s16x4 __attribute__((ext_vector_type(4)));
typedef float f32x4 __attribute__((ext_vector_type(4)));
typedef unsigned int u32;

static __device__ __forceinline__ f32x4 mfma32(bf16x8 a, bf16x8 b, f32x4 c) {
    return __builtin_amdgcn_mfma_f32_16x16x32_bf16(a, b, c, 0, 0, 0);
}

static __device__ __forceinline__ f32x4 mfma16(s16x4 a, s16x4 b, f32x4 c) {
#if __has_builtin(__builtin_amdgcn_mfma_f32_16x16x16bf16_1k)
    return __builtin_amdgcn_mfma_f32_16x16x16bf16_1k(a, b, c, 0, 0, 0);
#elif __has_builtin(__builtin_amdgcn_mfma_f32_16x16x16_bf16)
    return __builtin_amdgcn_mfma_f32_16x16x16_bf16(
        __builtin_bit_cast(bf16x4_t, a), __builtin_bit_cast(bf16x4_t, b), c, 0, 0, 0);
#else
    asm volatile("s_nop 1\n\tv_mfma_f32_16x16x16_bf16 %0, %1, %2, %0\n\ts_nop 7\n\ts_nop 7"
                 : "+v"(c) : "v"(a), "v"(b));
    return c;
#endif
}

// fast softplus (inputs bounded ~|x|<9 for this problem; overflow only at x>88)
static __device__ __forceinline__ u32 packsp(float x0, float x1) {
    float s0 = __logf(1.f + __expf(x0));
    float s1 = __logf(1.f + __expf(x1));
    union { __bf16 b[2]; u32 w; } u;
    u.b[0] = (__bf16)s0; u.b[1] = (__bf16)s1;
    return u.w;
}

static __device__ __forceinline__ s16x4 mk4(u32 lo, u32 hi) {
    union { u32 w[2]; s16x4 v; } u;
    u.w[0] = lo; u.w[1] = hi;
    return u.v;
}

// D=64, R=64, H=128, K1=192. hid^T = W1^T*edge^T (16x16x32); out^T = W2^T*hid^T (16x16x16).
// Pre-swizzled LDS frag layouts: frag = 16B at lane*16 + imm -> conflict-free ds_read_b128.
__global__ __launch_bounds__(512, 4) void edge_mlp_kernel(
    const float* __restrict__ node_feats,   // [N,64]
    const float* __restrict__ edge_feats,   // [E,64]
    const int* __restrict__ src_idx,        // [E]
    const int* __restrict__ dst_idx,        // [E]
    const float* __restrict__ W1,           // [192,128]
    const float* __restrict__ b1,           // [128]
    const float* __restrict__ W2,           // [128,64]
    const float* __restrict__ b2,           // [64]
    float* __restrict__ out,                // [E,64]
    int E, int nchunks)
{
    __shared__ alignas(16) __bf16 sW1f[8 * 6 * 64 * 8];   // 49152 B
    __shared__ alignas(16) __bf16 sW2f[4 * 4 * 64 * 8];   // 16384 B
    __shared__ alignas(16) __bf16 sB1f[8 * 64 * 4];       // 4096 B
    __shared__ alignas(16) __bf16 sB2f[4 * 64 * 4];       // 2048 B  (total 71680)

    const int tid  = threadIdx.x;
    const int lane = tid & 63;
    const int wid  = tid >> 6;

    // ---- stage pre-swizzled fragments (once per persistent block) ----
    for (int i = tid; i < 192 * 128; i += 512) {
        int k = i >> 7, h = i & 127;
        int n = h >> 4, r = h & 15, t = k >> 5, kq = (k >> 3) & 3, j = k & 7;
        sW1f[((n * 6 + t) * 64 + kq * 16 + r) * 8 + j] = (__bf16)W1[i];
    }
    for (int i = tid; i < 128 * 64; i += 512) {
        int h = i >> 6, r = i & 63;
        int rt = r >> 4, r16 = r & 15, n = h >> 4, hq = (h >> 2) & 3, j = h & 3;
        sW2f[((rt * 4 + (n >> 1)) * 64 + hq * 16 + r16) * 8 + (n & 1) * 4 + j] = (__bf16)W2[i];
    }
    for (int s = tid; s < 8 * 64 * 4; s += 512) {
        int j = s & 3, ln = (s >> 2) & 63, n = s >> 8;
        sB1f[s] = (j == 0 && ln < 16) ? (__bf16)b1[n * 16 + ln] : (__bf16)0.f;
    }
    for (int s = tid; s < 4 * 64 * 4; s += 512) {
        int j = s & 3, ln = (s >> 2) & 63, rt = s >> 8;
        sB2f[s] = (j == 0 && ln < 16) ? (__bf16)b2[rt * 16 + ln] : (__bf16)0.f;
    }
    __syncthreads();

    const int q   = lane >> 4;
    const int r16 = lane & 15;
    const int ko  = q * 8;

    const __bf16* w1p = &sW1f[lane * 8];
    const __bf16* w2p = &sW2f[lane * 8];
    const __bf16* b1p = &sB1f[lane * 4];
    const __bf16* b2p = &sB2f[lane * 4];

    const s16x4 one = {(short)(q == 0 ? 0x3F80 : 0), 0, 0, 0};

    // per-t gather offset from the 6 per-tile offsets
#define TOFF(T, S, Dd, Ee) ((T) < 2 ? (S) + (T) * 32 : (T) < 4 ? (Dd) + ((T) - 2) * 32 : (Ee) + ((T) - 4) * 32)

#define GL(T, B, S0, D0, E0o, S1, D1, E1o) {                                    \
        u32 a0 = TOFF(T, S0, D0, E0o), a1 = TOFF(T, S1, D1, E1o);               \
        const float* bp = ((T) < 4) ? node_feats : edge_feats;                  \
        B[0] = *(const f32x4*)(bp + a0); B[1] = *(const f32x4*)(bp + a0 + 4);   \
        B[2] = *(const f32x4*)(bp + a1); B[3] = *(const f32x4*)(bp + a1 + 4); }

    // compute on CUR; issue load T+2 into LD (only for T<4)
#define STEP(T, CUR, LD) {                                                      \
        if ((T) < 4) GL((T) + 2, LD, os0, od0, oe0, os1, od1, oe1);             \
        bf16x8 ef0, ef1;                                                        \
        _Pragma("unroll")                                                       \
        for (int j = 0; j < 4; ++j) {                                           \
            ef0[j] = (__bf16)CUR[0][j]; ef0[j + 4] = (__bf16)CUR[1][j];         \
            ef1[j] = (__bf16)CUR[2][j]; ef1[j + 4] = (__bf16)CUR[3][j];         \
        }                                                                       \
        _Pragma("unroll")                                                       \
        for (int n = 0; n < 8; ++n) {                                           \
            bf16x8 w = *(const bf16x8*)(w1p + (n * 6 + (T)) * 512);             \
            acc1[0][n] = mfma32(w, ef0, acc1[0][n]);                            \
            acc1[1][n] = mfma32(w, ef1, acc1[1][n]);                            \
        }                                                                       \
        __builtin_amdgcn_sched_barrier(0); }

    int c = blockIdx.x;
    u32 os0, od0, oe0, os1, od1, oe1;
    f32x4 G0[4], G1[4], G2[4];
    {
        int b = c * 256 + wid * 32;
        int e0 = b + r16, e1 = b + 16 + r16;
        int ie0 = e0 < E ? e0 : E - 1;
        int ie1 = e1 < E ? e1 : E - 1;
        os0 = (u32)src_idx[ie0] * 64 + ko; od0 = (u32)dst_idx[ie0] * 64 + ko;
        os1 = (u32)src_idx[ie1] * 64 + ko; od1 = (u32)dst_idx[ie1] * 64 + ko;
        oe0 = (u32)ie0 * 64 + ko;          oe1 = (u32)ie1 * 64 + ko;
        GL(0, G0, os0, od0, oe0, os1, od1, oe1);
        GL(1, G1, os0, od0, oe0, os1, od1, oe1);
    }

    while (c < nchunks) {
        const int base = c * 256 + wid * 32;

        // prefetch next chunk's indices early (loads in flight through GEMM1)
        const int cn = c + gridDim.x;
        u32 nos0 = os0, nod0 = od0, noe0 = oe0, nos1 = os1, nod1 = od1, noe1 = oe1;
        if (cn < nchunks) {
            int bb = cn * 256 + wid * 32;
            int e0 = bb + r16, e1 = bb + 16 + r16;
            int nie0 = e0 < E ? e0 : E - 1;
            int nie1 = e1 < E ? e1 : E - 1;
            nos0 = (u32)src_idx[nie0] * 64 + ko; nod0 = (u32)dst_idx[nie0] * 64 + ko;
            nos1 = (u32)src_idx[nie1] * 64 + ko; nod1 = (u32)dst_idx[nie1] * 64 + ko;
            noe0 = (u32)nie0 * 64 + ko;          noe1 = (u32)nie1 * 64 + ko;
        }

        f32x4 acc1[2][8];
#pragma unroll
        for (int m = 0; m < 2; ++m)
#pragma unroll
            for (int n = 0; n < 8; ++n) acc1[m][n] = (f32x4){0.f, 0.f, 0.f, 0.f};

        // ---- GEMM1: depth-2 rotating prefetch (t0,t1 already in flight) ----
        STEP(0, G0, G2);   // load t2
        STEP(1, G1, G0);   // load t3
        STEP(2, G2, G1);   // load t4
        STEP(3, G0, G2);   // load t5
        STEP(4, G1, G1);
        STEP(5, G2, G2);

        // bias1 as one 16-wide K-step
#pragma unroll
        for (int n = 0; n < 8; ++n) {
            s16x4 wb = *(const s16x4*)(b1p + n * 256);
            acc1[0][n] = mfma16(wb, one, acc1[0][n]);
            acc1[1][n] = mfma16(wb, one, acc1[1][n]);
        }

        // ---- softplus + pack; acc1 dies here ----
        u32 P[2][8][2];
#pragma unroll
        for (int m = 0; m < 2; ++m)
#pragma unroll
            for (int n = 0; n < 8; ++n) {
                P[m][n][0] = packsp(acc1[m][n][0], acc1[m][n][1]);
                P[m][n][1] = packsp(acc1[m][n][2], acc1[m][n][3]);
            }
        __builtin_amdgcn_sched_barrier(0);

        // ---- cross-phase prefetch: next tile's t0,t1 ride under GEMM2 ----
        if (cn < nchunks) {
            GL(0, G0, nos0, nod0, noe0, nos1, nod1, noe1);
            GL(1, G1, nos0, nod0, noe0, nos1, nod1, noe1);
        }

        // ---- GEMM2, rt-outer: 2 accumulators live; store immediately ----
        const int e0 = base + r16, e1 = base + 16 + r16;
        float* op0 = out + (size_t)e0 * 64 + q * 4;
        float* op1 = out + (size_t)e1 * 64 + q * 4;
#pragma unroll
        for (int rt = 0; rt < 4; ++rt) {
            f32x4 a20 = {0.f, 0.f, 0.f, 0.f};
            f32x4 a21 = {0.f, 0.f, 0.f, 0.f};
#pragma unroll
            for (int np = 0; np < 4; ++np) {
                union { bf16x8 v8; s16x4 h[2]; } uw;
                uw.v8 = *(const bf16x8*)(w2p + (rt * 4 + np) * 512);
                a20 = mfma16(uw.h[0], mk4(P[0][2 * np][0],     P[0][2 * np][1]),     a20);
                a20 = mfma16(uw.h[1], mk4(P[0][2 * np + 1][0], P[0][2 * np + 1][1]), a20);
                a21 = mfma16(uw.h[0], mk4(P[1][2 * np][0],     P[1][2 * np][1]),     a21);
                a21 = mfma16(uw.h[1], mk4(P[1][2 * np + 1][0], P[1][2 * np + 1][1]), a21);
            }
            s16x4 wb2 = *(const s16x4*)(b2p + rt * 256);
            a20 = mfma16(wb2, one, a20);
            a21 = mfma16(wb2, one, a21);
            if (e0 < E) *(f32x4*)(op0 + rt * 16) = a20;
            if (e1 < E) *(f32x4*)(op1 + rt * 16) = a21;
        }

        os0 = nos0; od0 = nod0; oe0 = noe0;
        os1 = nos1; od1 = nod1; oe1 = noe1;
        c = cn;
    }
#undef STEP
#undef GL
#undef TOFF
}

extern "C" void kernel_launch(void* const* d_in, const int* in_sizes, int n_in,
                              void* d_out, int out_size, void* d_ws, size_t ws_size,
                              hipStream_t stream) {
    const float* node_feats = (const float*)d_in[0];
    const float* edge_feats = (const float*)d_in[1];
    const int*   src_idx    = (const int*)d_in[2];
    const int*   dst_idx    = (const int*)d_in[3];
    const float* W1         = (const float*)d_in[4];
    const float* b1         = (const float*)d_in[5];
    const float* W2         = (const float*)d_in[6];
    const float* b2         = (const float*)d_in[7];
    float* out = (float*)d_out;

    const int E = in_sizes[2];
    const int nchunks = (E + 255) / 256;
    int grid = nchunks < 512 ? nchunks : 512;

    edge_mlp_kernel<<<grid, 512, 0, stream>>>(node_feats, edge_feats, src_idx, dst_idx,
                                              W1, b1, W2, b2, out, E, nchunks);
}

// Round 7
// 241.204 us; speedup vs baseline: 1.2178x; 1.2178x over previous
//
#include <hip/hip_runtime.h>
#include <hip/hip_bf16.h>

typedef __bf16 bf16x8 __attribute__((ext_vector_type(8)));
typedef __bf16 bf16x4_t __attribute__((ext_vector_type(4)));
typedef short s16x4 __attribute__((ext_vector_type(4)));
typedef float f32x4 __attribute__((ext_vector_type(4)));
typedef unsigned int u32;

static __device__ __forceinline__ f32x4 mfma32(bf16x8 a, bf16x8 b, f32x4 c) {
    return __builtin_amdgcn_mfma_f32_16x16x32_bf16(a, b, c, 0, 0, 0);
}

static __device__ __forceinline__ f32x4 mfma16(s16x4 a, s16x4 b, f32x4 c) {
#if __has_builtin(__builtin_amdgcn_mfma_f32_16x16x16bf16_1k)
    return __builtin_amdgcn_mfma_f32_16x16x16bf16_1k(a, b, c, 0, 0, 0);
#elif __has_builtin(__builtin_amdgcn_mfma_f32_16x16x16_bf16)
    return __builtin_amdgcn_mfma_f32_16x16x16_bf16(
        __builtin_bit_cast(bf16x4_t, a), __builtin_bit_cast(bf16x4_t, b), c, 0, 0, 0);
#else
    asm volatile("s_nop 1\n\tv_mfma_f32_16x16x16_bf16 %0, %1, %2, %0\n\ts_nop 7\n\ts_nop 7"
                 : "+v"(c) : "v"(a), "v"(b));
    return c;
#endif
}

// fast softplus (pre-activations bounded ~|x|<10 here; overflow only at x>88)
static __device__ __forceinline__ u32 packsp(float x0, float x1) {
    float s0 = __logf(1.f + __expf(x0));
    float s1 = __logf(1.f + __expf(x1));
    union { __bf16 b[2]; u32 w; } u;
    u.b[0] = (__bf16)s0; u.b[1] = (__bf16)s1;
    return u.w;
}

static __device__ __forceinline__ s16x4 mk4(u32 lo, u32 hi) {
    union { u32 w[2]; s16x4 v; } u;
    u.w[0] = lo; u.w[1] = hi;
    return u.v;
}

static __device__ __forceinline__ bf16x8 cvt8(const f32x4& a, const f32x4& b) {
    bf16x8 r;
#pragma unroll
    for (int j = 0; j < 4; ++j) { r[j] = (__bf16)a[j]; r[j + 4] = (__bf16)b[j]; }
    return r;
}

// D=64, R=64, H=128, K1=192. hid^T = W1^T*edge^T (16x16x32); out^T = W2^T*hid^T (16x16x16).
// K-step order {4,5,0,1,2,3}: edge_feats (HBM stream) consumed first from bf16 regs
// prefetched a FULL TILE ahead (index-independent addresses); node gathers depth-2.
__global__ __launch_bounds__(512, 4) void edge_mlp_kernel(
    const float* __restrict__ node_feats,   // [N,64]
    const float* __restrict__ edge_feats,   // [E,64]
    const int* __restrict__ src_idx,        // [E]
    const int* __restrict__ dst_idx,        // [E]
    const float* __restrict__ W1,           // [192,128]
    const float* __restrict__ b1,           // [128]
    const float* __restrict__ W2,           // [128,64]
    const float* __restrict__ b2,           // [64]
    float* __restrict__ out,                // [E,64]
    int E, int nchunks)
{
    __shared__ alignas(16) __bf16 sW1f[8 * 6 * 64 * 8];   // 49152 B
    __shared__ alignas(16) __bf16 sW2f[4 * 4 * 64 * 8];   // 16384 B
    __shared__ alignas(16) __bf16 sB1f[8 * 64 * 4];       // 4096 B
    __shared__ alignas(16) __bf16 sB2f[4 * 64 * 4];       // 2048 B  (total 71680)

    const int tid  = threadIdx.x;
    const int lane = tid & 63;
    const int wid  = tid >> 6;

    // ---- stage pre-swizzled fragments (once per persistent block) ----
    for (int i = tid; i < 192 * 128; i += 512) {
        int k = i >> 7, h = i & 127;
        int n = h >> 4, r = h & 15, t = k >> 5, kq = (k >> 3) & 3, j = k & 7;
        sW1f[((n * 6 + t) * 64 + kq * 16 + r) * 8 + j] = (__bf16)W1[i];
    }
    for (int i = tid; i < 128 * 64; i += 512) {
        int h = i >> 6, r = i & 63;
        int rt = r >> 4, r16 = r & 15, n = h >> 4, hq = (h >> 2) & 3, j = h & 3;
        sW2f[((rt * 4 + (n >> 1)) * 64 + hq * 16 + r16) * 8 + (n & 1) * 4 + j] = (__bf16)W2[i];
    }
    for (int s = tid; s < 8 * 64 * 4; s += 512) {
        int j = s & 3, ln = (s >> 2) & 63, n = s >> 8;
        sB1f[s] = (j == 0 && ln < 16) ? (__bf16)b1[n * 16 + ln] : (__bf16)0.f;
    }
    for (int s = tid; s < 4 * 64 * 4; s += 512) {
        int j = s & 3, ln = (s >> 2) & 63, rt = s >> 8;
        sB2f[s] = (j == 0 && ln < 16) ? (__bf16)b2[rt * 16 + ln] : (__bf16)0.f;
    }
    __syncthreads();

    const int q   = lane >> 4;
    const int r16 = lane & 15;
    const int ko  = q * 8;

    const __bf16* w1p = &sW1f[lane * 8];
    const __bf16* w2p = &sW2f[lane * 8];
    const __bf16* b1p = &sB1f[lane * 4];
    const __bf16* b2p = &sB2f[lane * 4];

    const s16x4 one = {(short)(q == 0 ? 0x3F80 : 0), 0, 0, 0};

    // MFMA cluster for weight k-block T with edge-data frags ef0 (m0), ef1 (m1)
#define MM(T, EF0, EF1) {                                                       \
        _Pragma("unroll")                                                       \
        for (int n = 0; n < 8; ++n) {                                           \
            bf16x8 w = *(const bf16x8*)(w1p + (n * 6 + (T)) * 512);             \
            acc1[0][n] = mfma32(w, EF0, acc1[0][n]);                            \
            acc1[1][n] = mfma32(w, EF1, acc1[1][n]);                            \
        }                                                                       \
        __builtin_amdgcn_sched_barrier(0); }

    int c = blockIdx.x;
    u32 os0, od0, os1, od1;           // node gather offsets (ko folded)
    bf16x8 EB00, EB01, EB10, EB11;    // edge_feats frags: EB<t><m>, t in {0(k4),1(k5)}
    {
        int b = c * 256 + wid * 32;
        int e0 = b + r16, e1 = b + 16 + r16;
        int ie0 = e0 < E ? e0 : E - 1;
        int ie1 = e1 < E ? e1 : E - 1;
        os0 = (u32)src_idx[ie0] * 64 + ko; od0 = (u32)dst_idx[ie0] * 64 + ko;
        os1 = (u32)src_idx[ie1] * 64 + ko; od1 = (u32)dst_idx[ie1] * 64 + ko;
        u32 oe0 = (u32)ie0 * 64 + ko, oe1 = (u32)ie1 * 64 + ko;
        f32x4 a = *(const f32x4*)(edge_feats + oe0);
        f32x4 bb = *(const f32x4*)(edge_feats + oe0 + 4);
        f32x4 cc = *(const f32x4*)(edge_feats + oe0 + 32);
        f32x4 d = *(const f32x4*)(edge_feats + oe0 + 36);
        f32x4 ee = *(const f32x4*)(edge_feats + oe1);
        f32x4 f = *(const f32x4*)(edge_feats + oe1 + 4);
        f32x4 g = *(const f32x4*)(edge_feats + oe1 + 32);
        f32x4 h = *(const f32x4*)(edge_feats + oe1 + 36);
        EB00 = cvt8(a, bb);  EB10 = cvt8(cc, d);
        EB01 = cvt8(ee, f);  EB11 = cvt8(g, h);
    }

    while (c < nchunks) {
        const int base = c * 256 + wid * 32;

        // ---- issue node loads for k-blocks 0,1 (src rows) ----
        f32x4 n0[4], n1[4];
        n0[0] = *(const f32x4*)(node_feats + os0);
        n0[1] = *(const f32x4*)(node_feats + os0 + 4);
        n0[2] = *(const f32x4*)(node_feats + os1);
        n0[3] = *(const f32x4*)(node_feats + os1 + 4);
        n1[0] = *(const f32x4*)(node_feats + os0 + 32);
        n1[1] = *(const f32x4*)(node_feats + os0 + 36);
        n1[2] = *(const f32x4*)(node_feats + os1 + 32);
        n1[3] = *(const f32x4*)(node_feats + os1 + 36);
        __builtin_amdgcn_sched_barrier(0);

        // ---- prefetch next chunk's indices (loads in flight through GEMM1) ----
        const int cn = c + gridDim.x;
        u32 nos0 = os0, nod0 = od0, nos1 = os1, nod1 = od1;
        int nie0, nie1;
        {
            int cc2 = cn < nchunks ? cn : c;
            int bb = cc2 * 256 + wid * 32;
            int e0 = bb + r16, e1 = bb + 16 + r16;
            nie0 = e0 < E ? e0 : E - 1;
            nie1 = e1 < E ? e1 : E - 1;
            nos0 = (u32)src_idx[nie0] * 64 + ko; nod0 = (u32)dst_idx[nie0] * 64 + ko;
            nos1 = (u32)src_idx[nie1] * 64 + ko; nod1 = (u32)dst_idx[nie1] * 64 + ko;
        }

        f32x4 acc1[2][8];
#pragma unroll
        for (int m = 0; m < 2; ++m)
#pragma unroll
            for (int n = 0; n < 8; ++n) acc1[m][n] = (f32x4){0.f, 0.f, 0.f, 0.f};

        // ---- GEMM1, K order {4,5,0,1,2,3} ----
        MM(4, EB00, EB01);                       // pure reg+LDS: covers n0,n1
        MM(5, EB10, EB11);
        f32x4 n2[4], n3[4];
        {   // k-block 0: consume n0, issue dst k-block 2
            bf16x8 ef0 = cvt8(n0[0], n0[1]), ef1 = cvt8(n0[2], n0[3]);
            n2[0] = *(const f32x4*)(node_feats + od0);
            n2[1] = *(const f32x4*)(node_feats + od0 + 4);
            n2[2] = *(const f32x4*)(node_feats + od1);
            n2[3] = *(const f32x4*)(node_feats + od1 + 4);
            MM(0, ef0, ef1);
        }
        {   // k-block 1: consume n1, issue dst k-block 3
            bf16x8 ef0 = cvt8(n1[0], n1[1]), ef1 = cvt8(n1[2], n1[3]);
            n3[0] = *(const f32x4*)(node_feats + od0 + 32);
            n3[1] = *(const f32x4*)(node_feats + od0 + 36);
            n3[2] = *(const f32x4*)(node_feats + od1 + 32);
            n3[3] = *(const f32x4*)(node_feats + od1 + 36);
            MM(1, ef0, ef1);
        }
        {   bf16x8 ef0 = cvt8(n2[0], n2[1]), ef1 = cvt8(n2[2], n2[3]);
            MM(2, ef0, ef1); }
        {   bf16x8 ef0 = cvt8(n3[0], n3[1]), ef1 = cvt8(n3[2], n3[3]);
            MM(3, ef0, ef1); }

        // bias1 as one 16-wide K-step
#pragma unroll
        for (int n = 0; n < 8; ++n) {
            s16x4 wb = *(const s16x4*)(b1p + n * 256);
            acc1[0][n] = mfma16(wb, one, acc1[0][n]);
            acc1[1][n] = mfma16(wb, one, acc1[1][n]);
        }

        // ---- softplus + pack; acc1 dies here ----
        u32 P[2][8][2];
#pragma unroll
        for (int m = 0; m < 2; ++m)
#pragma unroll
            for (int n = 0; n < 8; ++n) {
                P[m][n][0] = packsp(acc1[m][n][0], acc1[m][n][1]);
                P[m][n][1] = packsp(acc1[m][n][2], acc1[m][n][3]);
            }
        __builtin_amdgcn_sched_barrier(0);

        // ---- full-tile-ahead edge_feats prefetch (index-independent, HBM stream) ----
        const u32 noe0 = (u32)nie0 * 64 + ko, noe1 = (u32)nie1 * 64 + ko;
        f32x4 EN0[4], EN1[4];
        EN0[0] = __builtin_nontemporal_load((const f32x4*)(edge_feats + noe0));
        EN0[1] = __builtin_nontemporal_load((const f32x4*)(edge_feats + noe0 + 4));
        EN0[2] = __builtin_nontemporal_load((const f32x4*)(edge_feats + noe0 + 32));
        EN0[3] = __builtin_nontemporal_load((const f32x4*)(edge_feats + noe0 + 36));
        EN1[0] = __builtin_nontemporal_load((const f32x4*)(edge_feats + noe1));
        EN1[1] = __builtin_nontemporal_load((const f32x4*)(edge_feats + noe1 + 4));
        EN1[2] = __builtin_nontemporal_load((const f32x4*)(edge_feats + noe1 + 32));
        EN1[3] = __builtin_nontemporal_load((const f32x4*)(edge_feats + noe1 + 36));
        __builtin_amdgcn_sched_barrier(0);

        // ---- GEMM2, rt-outer: 2 accumulators live; nontemporal store ----
        const int e0 = base + r16, e1 = base + 16 + r16;
        float* op0 = out + (size_t)e0 * 64 + q * 4;
        float* op1 = out + (size_t)e1 * 64 + q * 4;
#pragma unroll
        for (int rt = 0; rt < 4; ++rt) {
            f32x4 a20 = {0.f, 0.f, 0.f, 0.f};
            f32x4 a21 = {0.f, 0.f, 0.f, 0.f};
#pragma unroll
            for (int np = 0; np < 4; ++np) {
                union { bf16x8 v8; s16x4 h[2]; } uw;
                uw.v8 = *(const bf16x8*)(w2p + (rt * 4 + np) * 512);
                a20 = mfma16(uw.h[0], mk4(P[0][2 * np][0],     P[0][2 * np][1]),     a20);
                a20 = mfma16(uw.h[1], mk4(P[0][2 * np + 1][0], P[0][2 * np + 1][1]), a20);
                a21 = mfma16(uw.h[0], mk4(P[1][2 * np][0],     P[1][2 * np][1]),     a21);
                a21 = mfma16(uw.h[1], mk4(P[1][2 * np + 1][0], P[1][2 * np + 1][1]), a21);
            }
            s16x4 wb2 = *(const s16x4*)(b2p + rt * 256);
            a20 = mfma16(wb2, one, a20);
            a21 = mfma16(wb2, one, a21);
            if (e0 < E) __builtin_nontemporal_store(a20, (f32x4*)(op0 + rt * 16));
            if (e1 < E) __builtin_nontemporal_store(a21, (f32x4*)(op1 + rt * 16));
        }
        __builtin_amdgcn_sched_barrier(0);

        // ---- convert prefetched edge data for next tile ----
        EB00 = cvt8(EN0[0], EN0[1]);  EB10 = cvt8(EN0[2], EN0[3]);
        EB01 = cvt8(EN1[0], EN1[1]);  EB11 = cvt8(EN1[2], EN1[3]);

        os0 = nos0; od0 = nod0; os1 = nos1; od1 = nod1;
        c = cn;
    }
#undef MM
}

extern "C" void kernel_launch(void* const* d_in, const int* in_sizes, int n_in,
                              void* d_out, int out_size, void* d_ws, size_t ws_size,
                              hipStream_t stream) {
    const float* node_feats = (const float*)d_in[0];
    const float* edge_feats = (const float*)d_in[1];
    const int*   src_idx    = (const int*)d_in[2];
    const int*   dst_idx    = (const int*)d_in[3];
    const float* W1         = (const float*)d_in[4];
    const float* b1         = (const float*)d_in[5];
    const float* W2         = (const float*)d_in[6];
    const float* b2         = (const float*)d_in[7];
    float* out = (float*)d_out;

    const int E = in_sizes[2];
    const int nchunks = (E + 255) / 256;
    int grid = nchunks < 512 ? nchunks : 512;

    edge_mlp_kernel<<<grid, 512, 0, stream>>>(node_feats, edge_feats, src_idx, dst_idx,
                                              W1, b1, W2, b2, out, E, nchunks);
}

// Round 8
// 176.444 us; speedup vs baseline: 1.6648x; 1.3670x over previous
//
#include <hip/hip_runtime.h>
#include <hip/hip_bf16.h>

typedef __bf16 bf16x8 __attribute__((ext_vector_type(8)));
typedef __bf16 bf16x4_t __attribute__((ext_vector_type(4)));
typedef short s16x4 __attribute__((ext_vector_type(4)));
typedef float f32x4 __attribute__((ext_vector_type(4)));
typedef unsigned int u32;

static __device__ __forceinline__ f32x4 mfma32(bf16x8 a, bf16x8 b, f32x4 c) {
    return __builtin_amdgcn_mfma_f32_16x16x32_bf16(a, b, c, 0, 0, 0);
}

static __device__ __forceinline__ f32x4 mfma16(s16x4 a, s16x4 b, f32x4 c) {
#if __has_builtin(__builtin_amdgcn_mfma_f32_16x16x16bf16_1k)
    return __builtin_amdgcn_mfma_f32_16x16x16bf16_1k(a, b, c, 0, 0, 0);
#elif __has_builtin(__builtin_amdgcn_mfma_f32_16x16x16_bf16)
    return __builtin_amdgcn_mfma_f32_16x16x16_bf16(
        __builtin_bit_cast(bf16x4_t, a), __builtin_bit_cast(bf16x4_t, b), c, 0, 0, 0);
#else
    asm volatile("s_nop 1\n\tv_mfma_f32_16x16x16_bf16 %0, %1, %2, %0\n\ts_nop 7\n\ts_nop 7"
                 : "+v"(c) : "v"(a), "v"(b));
    return c;
#endif
}

// fast softplus (pre-activations bounded ~|x|<10 here; overflow only at x>88)
static __device__ __forceinline__ u32 packsp(float x0, float x1) {
    float s0 = __logf(1.f + __expf(x0));
    float s1 = __logf(1.f + __expf(x1));
    union { __bf16 b[2]; u32 w; } u;
    u.b[0] = (__bf16)s0; u.b[1] = (__bf16)s1;
    return u.w;
}

static __device__ __forceinline__ s16x4 mk4(u32 lo, u32 hi) {
    union { u32 w[2]; s16x4 v; } u;
    u.w[0] = lo; u.w[1] = hi;
    return u.v;
}

static __device__ __forceinline__ bf16x8 cvt8(const f32x4& a, const f32x4& b) {
    bf16x8 r;
#pragma unroll
    for (int j = 0; j < 4; ++j) { r[j] = (__bf16)a[j]; r[j + 4] = (__bf16)b[j]; }
    return r;
}

// ---- pre-pass: node_feats f32 -> bf16 (into d_ws). 3.2M elems, ~19 MB moved ----
__global__ __launch_bounds__(256) void cvt_nodes_kernel(const float* __restrict__ in,
                                                        __bf16* __restrict__ outb, int n8) {
    int i = blockIdx.x * 256 + threadIdx.x;
    if (i < n8) {
        const f32x4* p = (const f32x4*)(in + (size_t)i * 8);
        f32x4 a = p[0], b = p[1];
        *(bf16x8*)(outb + (size_t)i * 8) = cvt8(a, b);
    }
}

// D=64, R=64, H=128, K1=192. hid^T = W1^T*edge^T (16x16x32); out^T = W2^T*hid^T (16x16x16).
// Nodes gathered as bf16 (pre-converted): one 16B load per fragment, zero cvt.
// Edge stream (index-independent addresses) prefetched a full tile ahead.
__global__ __launch_bounds__(512, 4) void edge_mlp_kernel(
    const __bf16* __restrict__ nb,          // [N,64] bf16 (pre-converted)
    const float* __restrict__ edge_feats,   // [E,64] f32
    const int* __restrict__ src_idx,        // [E]
    const int* __restrict__ dst_idx,        // [E]
    const float* __restrict__ W1,           // [192,128]
    const float* __restrict__ b1,           // [128]
    const float* __restrict__ W2,           // [128,64]
    const float* __restrict__ b2,           // [64]
    float* __restrict__ out,                // [E,64]
    int E, int nchunks)
{
    __shared__ alignas(16) __bf16 sW1f[8 * 6 * 64 * 8];   // 49152 B
    __shared__ alignas(16) __bf16 sW2f[4 * 4 * 64 * 8];   // 16384 B
    __shared__ alignas(16) __bf16 sB1f[8 * 64 * 4];       // 4096 B
    __shared__ alignas(16) __bf16 sB2f[4 * 64 * 4];       // 2048 B  (total 71680)

    const int tid  = threadIdx.x;
    const int lane = tid & 63;
    const int wid  = tid >> 6;

    // ---- stage pre-swizzled weight fragments (once per persistent block) ----
    for (int i = tid; i < 192 * 128; i += 512) {
        int k = i >> 7, h = i & 127;
        int n = h >> 4, r = h & 15, t = k >> 5, kq = (k >> 3) & 3, j = k & 7;
        sW1f[((n * 6 + t) * 64 + kq * 16 + r) * 8 + j] = (__bf16)W1[i];
    }
    for (int i = tid; i < 128 * 64; i += 512) {
        int h = i >> 6, r = i & 63;
        int rt = r >> 4, r16 = r & 15, n = h >> 4, hq = (h >> 2) & 3, j = h & 3;
        sW2f[((rt * 4 + (n >> 1)) * 64 + hq * 16 + r16) * 8 + (n & 1) * 4 + j] = (__bf16)W2[i];
    }
    for (int s = tid; s < 8 * 64 * 4; s += 512) {
        int j = s & 3, ln = (s >> 2) & 63, n = s >> 8;
        sB1f[s] = (j == 0 && ln < 16) ? (__bf16)b1[n * 16 + ln] : (__bf16)0.f;
    }
    for (int s = tid; s < 4 * 64 * 4; s += 512) {
        int j = s & 3, ln = (s >> 2) & 63, rt = s >> 8;
        sB2f[s] = (j == 0 && ln < 16) ? (__bf16)b2[rt * 16 + ln] : (__bf16)0.f;
    }
    __syncthreads();

    const int q   = lane >> 4;
    const int r16 = lane & 15;
    const int ko  = q * 8;

    const __bf16* w1p = &sW1f[lane * 8];
    const __bf16* w2p = &sW2f[lane * 8];
    const __bf16* b1p = &sB1f[lane * 4];
    const __bf16* b2p = &sB2f[lane * 4];

    const s16x4 one = {(short)(q == 0 ? 0x3F80 : 0), 0, 0, 0};

#define MM(T, EF0, EF1) {                                                       \
        _Pragma("unroll")                                                       \
        for (int n = 0; n < 8; ++n) {                                           \
            bf16x8 w = *(const bf16x8*)(w1p + (n * 6 + (T)) * 512);             \
            acc1[0][n] = mfma32(w, EF0, acc1[0][n]);                            \
            acc1[1][n] = mfma32(w, EF1, acc1[1][n]);                            \
        }                                                                       \
        __builtin_amdgcn_sched_barrier(0); }

    int c = blockIdx.x;
    u32 os0, od0, os1, od1;           // node gather offsets (bf16 elements, ko folded)
    bf16x8 EB00, EB01, EB10, EB11;    // edge frags: EB<t><m>, t in {0(k4),1(k5)}
    {
        int b = c * 256 + wid * 32;
        int e0 = b + r16, e1 = b + 16 + r16;
        int ie0 = e0 < E ? e0 : E - 1;
        int ie1 = e1 < E ? e1 : E - 1;
        os0 = (u32)src_idx[ie0] * 64 + ko; od0 = (u32)dst_idx[ie0] * 64 + ko;
        os1 = (u32)src_idx[ie1] * 64 + ko; od1 = (u32)dst_idx[ie1] * 64 + ko;
        u32 oe0 = (u32)ie0 * 64 + ko, oe1 = (u32)ie1 * 64 + ko;
        f32x4 a  = *(const f32x4*)(edge_feats + oe0);
        f32x4 bb = *(const f32x4*)(edge_feats + oe0 + 4);
        f32x4 cc = *(const f32x4*)(edge_feats + oe0 + 32);
        f32x4 d  = *(const f32x4*)(edge_feats + oe0 + 36);
        f32x4 ee = *(const f32x4*)(edge_feats + oe1);
        f32x4 f  = *(const f32x4*)(edge_feats + oe1 + 4);
        f32x4 g  = *(const f32x4*)(edge_feats + oe1 + 32);
        f32x4 h  = *(const f32x4*)(edge_feats + oe1 + 36);
        EB00 = cvt8(a, bb);  EB10 = cvt8(cc, d);
        EB01 = cvt8(ee, f);  EB11 = cvt8(g, h);
    }

    while (c < nchunks) {
        const int base = c * 256 + wid * 32;

        // ---- issue all 8 node gather loads (bf16 rows: 16B = one full fragment) ----
        bf16x8 NS0a = *(const bf16x8*)(nb + os0);
        bf16x8 NS0b = *(const bf16x8*)(nb + os0 + 32);
        bf16x8 NS1a = *(const bf16x8*)(nb + os1);
        bf16x8 NS1b = *(const bf16x8*)(nb + os1 + 32);
        bf16x8 ND0a = *(const bf16x8*)(nb + od0);
        bf16x8 ND0b = *(const bf16x8*)(nb + od0 + 32);
        bf16x8 ND1a = *(const bf16x8*)(nb + od1);
        bf16x8 ND1b = *(const bf16x8*)(nb + od1 + 32);
        __builtin_amdgcn_sched_barrier(0);

        f32x4 acc1[2][8];
#pragma unroll
        for (int m = 0; m < 2; ++m)
#pragma unroll
            for (int n = 0; n < 8; ++n) acc1[m][n] = (f32x4){0.f, 0.f, 0.f, 0.f};

        // ---- GEMM1, K order {4,5,0,1,2,3}: edge-in-reg first, node gathers covered ----
        MM(4, EB00, EB01);
        MM(5, EB10, EB11);
        MM(0, NS0a, NS1a);
        MM(1, NS0b, NS1b);
        MM(2, ND0a, ND1a);
        MM(3, ND0b, ND1b);

        // bias1 as one 16-wide K-step
#pragma unroll
        for (int n = 0; n < 8; ++n) {
            s16x4 wb = *(const s16x4*)(b1p + n * 256);
            acc1[0][n] = mfma16(wb, one, acc1[0][n]);
            acc1[1][n] = mfma16(wb, one, acc1[1][n]);
        }

        // ---- softplus + pack; acc1 dies here ----
        u32 P[2][8][2];
#pragma unroll
        for (int m = 0; m < 2; ++m)
#pragma unroll
            for (int n = 0; n < 8; ++n) {
                P[m][n][0] = packsp(acc1[m][n][0], acc1[m][n][1]);
                P[m][n][1] = packsp(acc1[m][n][2], acc1[m][n][3]);
            }
        __builtin_amdgcn_sched_barrier(0);

        // ---- next tile's edge prefetch: address is pure arithmetic, issue NOW ----
        const int cn = c + gridDim.x;
        const int cc2 = cn < nchunks ? cn : c;
        const int bb2 = cc2 * 256 + wid * 32;
        const int pe0 = bb2 + r16 < E ? bb2 + r16 : E - 1;
        const int pe1 = bb2 + 16 + r16 < E ? bb2 + 16 + r16 : E - 1;
        const u32 noe0 = (u32)pe0 * 64 + ko, noe1 = (u32)pe1 * 64 + ko;
        f32x4 EN0[4], EN1[4];
        EN0[0] = __builtin_nontemporal_load((const f32x4*)(edge_feats + noe0));
        EN0[1] = __builtin_nontemporal_load((const f32x4*)(edge_feats + noe0 + 4));
        EN0[2] = __builtin_nontemporal_load((const f32x4*)(edge_feats + noe0 + 32));
        EN0[3] = __builtin_nontemporal_load((const f32x4*)(edge_feats + noe0 + 36));
        EN1[0] = __builtin_nontemporal_load((const f32x4*)(edge_feats + noe1));
        EN1[1] = __builtin_nontemporal_load((const f32x4*)(edge_feats + noe1 + 4));
        EN1[2] = __builtin_nontemporal_load((const f32x4*)(edge_feats + noe1 + 32));
        EN1[3] = __builtin_nontemporal_load((const f32x4*)(edge_feats + noe1 + 36));
        __builtin_amdgcn_sched_barrier(0);

        // ---- next tile's index gathers (needed only at next tile top) ----
        u32 nos0 = (u32)src_idx[pe0] * 64 + ko;
        u32 nod0 = (u32)dst_idx[pe0] * 64 + ko;
        u32 nos1 = (u32)src_idx[pe1] * 64 + ko;
        u32 nod1 = (u32)dst_idx[pe1] * 64 + ko;

        // ---- GEMM2, rt-outer: 2 accumulators live; nontemporal stores ----
        const int e0 = base + r16, e1 = base + 16 + r16;
        float* op0 = out + (size_t)e0 * 64 + q * 4;
        float* op1 = out + (size_t)e1 * 64 + q * 4;
#pragma unroll
        for (int rt = 0; rt < 4; ++rt) {
            f32x4 a20 = {0.f, 0.f, 0.f, 0.f};
            f32x4 a21 = {0.f, 0.f, 0.f, 0.f};
#pragma unroll
            for (int np = 0; np < 4; ++np) {
                union { bf16x8 v8; s16x4 h[2]; } uw;
                uw.v8 = *(const bf16x8*)(w2p + (rt * 4 + np) * 512);
                a20 = mfma16(uw.h[0], mk4(P[0][2 * np][0],     P[0][2 * np][1]),     a20);
                a20 = mfma16(uw.h[1], mk4(P[0][2 * np + 1][0], P[0][2 * np + 1][1]), a20);
                a21 = mfma16(uw.h[0], mk4(P[1][2 * np][0],     P[1][2 * np][1]),     a21);
                a21 = mfma16(uw.h[1], mk4(P[1][2 * np + 1][0], P[1][2 * np + 1][1]), a21);
            }
            s16x4 wb2 = *(const s16x4*)(b2p + rt * 256);
            a20 = mfma16(wb2, one, a20);
            a21 = mfma16(wb2, one, a21);
            if (e0 < E) __builtin_nontemporal_store(a20, (f32x4*)(op0 + rt * 16));
            if (e1 < E) __builtin_nontemporal_store(a21, (f32x4*)(op1 + rt * 16));
        }
        __builtin_amdgcn_sched_barrier(0);

        // ---- convert prefetched edge data for next tile ----
        EB00 = cvt8(EN0[0], EN0[1]);  EB10 = cvt8(EN0[2], EN0[3]);
        EB01 = cvt8(EN1[0], EN1[1]);  EB11 = cvt8(EN1[2], EN1[3]);

        os0 = nos0; od0 = nod0; os1 = nos1; od1 = nod1;
        c = cn;
    }
#undef MM
}

extern "C" void kernel_launch(void* const* d_in, const int* in_sizes, int n_in,
                              void* d_out, int out_size, void* d_ws, size_t ws_size,
                              hipStream_t stream) {
    const float* node_feats = (const float*)d_in[0];
    const float* edge_feats = (const float*)d_in[1];
    const int*   src_idx    = (const int*)d_in[2];
    const int*   dst_idx    = (const int*)d_in[3];
    const float* W1         = (const float*)d_in[4];
    const float* b1         = (const float*)d_in[5];
    const float* W2         = (const float*)d_in[6];
    const float* b2         = (const float*)d_in[7];
    float* out = (float*)d_out;

    const int E = in_sizes[2];
    const int n8 = in_sizes[0] / 8;          // node elements / 8
    __bf16* node_bf = (__bf16*)d_ws;         // N*64*2 B = 6.4 MB scratch

    cvt_nodes_kernel<<<(n8 + 255) / 256, 256, 0, stream>>>(node_feats, node_bf, n8);

    const int nchunks = (E + 255) / 256;
    int grid = nchunks < 512 ? nchunks : 512;
    edge_mlp_kernel<<<grid, 512, 0, stream>>>(node_bf, edge_feats, src_idx, dst_idx,
                                              W1, b1, W2, b2, out, E, nchunks);
}